// Round 4
// baseline (187.870 us; speedup 1.0000x reference)
//
#include <hip/hip_runtime.h>

// Problem constants (inputs: (32,64,32,32) fp32; embed: (64,1024) fp32)
#define N_PIX  32768   // B*H*W
#define C_DIM  64
#define K_EMB  1024
#define HW     1024    // H*W
#define PIXB   64      // pixels per block
#define WAVES  8       // 512 threads

// d_out layout (float32, concatenated in return order):
//   quantized_out (B,C,H,W) | loss | encoding_indices | perplexity
#define OUT_Q_OFF    0
#define OUT_LOSS_OFF 2097152
#define OUT_IDX_OFF  2097153
#define OUT_PERP_OFF 2129921

typedef __attribute__((ext_vector_type(8)))  __bf16 bf16x8;
typedef __attribute__((ext_vector_type(16))) float  f32x16;

// g_esplit: bf16x3 split of embed, A-fragment-packed:
//   [j][tile(32 codes)][s(k/16)][h(k8 half)][c32][e(8)] -> 3*65536 shorts = 384 KB
__device__ unsigned short g_esplit[3 * K_EMB * C_DIM];
__device__ uint4          g_eesplit[2 * K_EMB];  // ee-slice A frags; [h][code], h=1 zero
__device__ float          g_ee[K_EMB];     // ||e_k||^2, fp32 fmaf chain (c-order)
__device__ unsigned int   g_counts[K_EMB];
__device__ float          g_lossAcc;

__device__ __forceinline__ unsigned short f2bf(float f) {   // RNE f32->bf16
    unsigned u = __float_as_uint(f);
    unsigned r = u + 0x7FFFu + ((u >> 16) & 1u);
    return (unsigned short)(r >> 16);
}
__device__ __forceinline__ float bf2f(unsigned short b) {
    return __uint_as_float(((unsigned)b) << 16);
}
__device__ __forceinline__ unsigned long long pack_score(float d, int k) {
    unsigned int u = __float_as_uint(d);
    u = (u & 0x80000000u) ? ~u : (u | 0x80000000u);  // monotone map, negative-safe
    return ((unsigned long long)u << 32) | (unsigned int)k;
}
__device__ __forceinline__ uint4 pack8(const unsigned short* v) {
    uint4 u;
    u.x = (unsigned)v[0] | ((unsigned)v[1] << 16);
    u.y = (unsigned)v[2] | ((unsigned)v[3] << 16);
    u.z = (unsigned)v[4] | ((unsigned)v[5] << 16);
    u.w = (unsigned)v[6] | ((unsigned)v[7] << 16);
    return u;
}
__device__ __forceinline__ unsigned long long shfl_xor32_u64(unsigned long long v) {
    unsigned lo = (unsigned)v, hi = (unsigned)(v >> 32);
    lo = __shfl_xor(lo, 32, 64);
    hi = __shfl_xor(hi, 32, 64);
    return ((unsigned long long)hi << 32) | lo;
}
// keep (P1 <= P2) as the two smallest seen so far
#define UPD2(P1, P2, MM) { \
    if ((MM) < P1) { P2 = P1; P1 = (MM); } else if ((MM) < P2) P2 = (MM); }
// merge sorted pair (o1<=o2) into (P1<=P2)
#define MRG2(P1, P2, O1, O2) { \
    unsigned long long _lo = (O1) < P1 ? (O1) : P1; \
    unsigned long long _hi = (O1) < P1 ? P1 : (O1); \
    unsigned long long _m2 = (O2) < P2 ? (O2) : P2; \
    P1 = _lo; P2 = _hi < _m2 ? _hi : _m2; }

// Split embed into bf16x3 A-fragment layout (uint4 stores) + ||e||^2 chain
// + ee-slice MFMA fragment (-0.5*||e||^2 split bf16x3 at K-elems 0..2).
__global__ void k_prep(const float* __restrict__ embed) {
    const int code = blockIdx.x * 64 + threadIdx.x;   // grid 16 x 64 -> 0..1023
    if (code == 0) g_lossAcc = 0.f;
    g_counts[code] = 0u;
    const int tile = code >> 5, c32 = code & 31;
    uint4* o = reinterpret_cast<uint4*>(g_esplit);
    float ee = 0.f;
#pragma unroll
    for (int s = 0; s < 4; ++s)
#pragma unroll
        for (int hh = 0; hh < 2; ++hh) {
            unsigned short b1[8], b2[8], b3[8];
#pragma unroll
            for (int e = 0; e < 8; ++e) {
                const float x = embed[(s * 16 + hh * 8 + e) * K_EMB + code];
                ee = fmaf(x, x, ee);                  // sequential c-order chain
                b1[e] = f2bf(x);
                const float r1 = x - bf2f(b1[e]);
                b2[e] = f2bf(r1);
                const float r2 = r1 - bf2f(b2[e]);
                b3[e] = f2bf(r2);
            }
            const int oi = tile * 256 + s * 64 + hh * 32 + c32;
            o[oi        ] = pack8(b1);
            o[oi +  8192] = pack8(b2);
            o[oi + 16384] = pack8(b3);
        }
    g_ee[code] = ee;
    // ee-slice A fragment: -0.5*ee split bf16x3 at K elements 0,1,2 (h=0 half)
    const float v = -0.5f * ee;
    const unsigned short e1 = f2bf(v);
    const float r1 = v - bf2f(e1);
    const unsigned short e2 = f2bf(r1);
    const float r2 = r1 - bf2f(e2);
    const unsigned short e3 = f2bf(r2);
    g_eesplit[code] = make_uint4((unsigned)e1 | ((unsigned)e2 << 16),
                                 (unsigned)e3, 0u, 0u);
    g_eesplit[K_EMB + code] = make_uint4(0u, 0u, 0u, 0u);
}

// Main: 64 pixels x 1024 codes per block. 8 waves/block, 2 blocks/CU ->
// 4 waves/SIMD (2x R2's TLP). No cross-iter prefetch (R3's spill lesson);
// registers budgeted for the 128-VGPR cap 4 waves/SIMD requires.
__global__ __launch_bounds__(512, 4) void k_main(
    const float* __restrict__ inp, const float* __restrict__ embed,
    float* __restrict__ out_q, float* __restrict__ out_idx) {

    __shared__ float x_raw[C_DIM * PIXB];          // 16 KB raw fp32 tile [c][p]
    __shared__ uint4 xfrag[3 * 4 * 2 * PIXB];      // 24 KB [j][s][h][p] -> 16B frags
    __shared__ unsigned long long red1[WAVES][PIXB];  // 4 KB per-wave top-1
    __shared__ unsigned long long red2[WAVES][PIXB];  // 4 KB per-wave top-2
    __shared__ int   ksel[PIXB];
    __shared__ float lred[WAVES];
    __shared__ float bdist;

    const int tid = threadIdx.x;
    const int n0  = blockIdx.x * PIXB;
    const int b   = n0 >> 10;
    const int hw0 = n0 & 1023;
    const float* __restrict__ xg = inp + b * (C_DIM * HW) + hw0;

    // ---- stage 1: coalesced raw tile load -> LDS (1024 float4, 512 thr x 2)
#pragma unroll
    for (int i = 0; i < 2; ++i) {
        const int F = tid + i * 512;               // float4 index 0..1023
        const int c = F >> 4, p4 = (F & 15) << 2;
        *reinterpret_cast<float4*>(&x_raw[F << 2]) =
            *reinterpret_cast<const float4*>(xg + c * HW + p4);
    }
    __syncthreads();

    // ---- stage 2: bf16x3 split into B-fragment layout + ||x||^2 partial
    float sx2 = 0.f;
    {
        const int s = tid >> 7, hh = (tid >> 6) & 1, p = tid & 63;  // 512 slots
        unsigned short b1[8], b2[8], b3[8];
#pragma unroll
        for (int e = 0; e < 8; ++e) {
            const float x = x_raw[(s * 16 + hh * 8 + e) * PIXB + p];
            sx2 = fmaf(x, x, sx2);
            b1[e] = f2bf(x);
            const float r1 = x - bf2f(b1[e]);
            b2[e] = f2bf(r1);
            const float r2 = r1 - bf2f(b2[e]);
            b3[e] = f2bf(r2);
        }
        const int fi = (s * 2 + hh) * PIXB + p;    // within one j-plane (8*PIXB)
        xfrag[fi            ] = pack8(b1);
        xfrag[fi + 8 * PIXB ] = pack8(b2);
        xfrag[fi + 16 * PIXB] = pack8(b3);
    }
    for (int off = 32; off; off >>= 1) sx2 += __shfl_down(sx2, off, 64);
    if ((tid & 63) == 0) lred[tid >> 6] = sx2;
    __syncthreads();

    // ---- distance GEMM + running top-2 (score = -(dot - ee/2))
    const int w   = tid >> 6;                      // wave 0..7
    const int ln  = tid & 63;
    const int c31 = ln & 31;
    const int h   = ln >> 5;
    const uint4* __restrict__ eg = reinterpret_cast<const uint4*>(g_esplit);
    const int abase = h * 32 + c31;

    unsigned long long p1a = ~0ull, p2a = ~0ull;   // pt=0 pixel top-2
    unsigned long long p1b = ~0ull, p2b = ~0ull;   // pt=1 pixel top-2
    const uint4 bones = make_uint4(h ? 0u : 0x3F803F80u, h ? 0u : 0x00003F80u, 0u, 0u);

#define MFMA1(AF, BF) \
    acc = __builtin_amdgcn_mfma_f32_32x32x16_bf16( \
        __builtin_bit_cast(bf16x8, AF), __builtin_bit_cast(bf16x8, BF), acc, 0, 0, 0);

#pragma unroll 1
    for (int r = 0; r < 4; ++r) {
        const int ct = r * 8 + w;                  // this wave's code tile 0..31
        const int b0 = ct * 256 + abase;
        const int cb = ct * 32;
        // A fragments for this tile: j0, j1, j2, ee (17 x uint4, issued up front)
        uint4 ae0[4], ae1[4], a2[4], aee;
#pragma unroll
        for (int s = 0; s < 4; ++s) {
            ae0[s] = eg[b0 + s * 64];
            ae1[s] = eg[b0 + 8192 + s * 64];
            a2[s]  = eg[b0 + 16384 + s * 64];
        }
        aee = g_eesplit[h * K_EMB + ct * 32 + c31];

#pragma unroll
        for (int pt = 0; pt < 2; ++pt) {
            const int pbase = pt * 32 + c31;
            f32x16 acc = {};
            MFMA1(aee, bones)
            {   // (0,0),(1,0) then drop bx0 (re-read later for (2,0))
                uint4 bx[4];
#pragma unroll
                for (int s = 0; s < 4; ++s) bx[s] = xfrag[(s * 2 + h) * PIXB + pbase];
#pragma unroll
                for (int s = 0; s < 4; ++s) { MFMA1(ae0[s], bx[s]) }
#pragma unroll
                for (int s = 0; s < 4; ++s) { MFMA1(ae1[s], bx[s]) }
            }
            {   // (0,1),(1,1)
                uint4 bx[4];
#pragma unroll
                for (int s = 0; s < 4; ++s) bx[s] = xfrag[(8 + s * 2 + h) * PIXB + pbase];
#pragma unroll
                for (int s = 0; s < 4; ++s) { MFMA1(ae0[s], bx[s]) }
#pragma unroll
                for (int s = 0; s < 4; ++s) { MFMA1(ae1[s], bx[s]) }
            }
            {   // (0,2)
                uint4 bx[4];
#pragma unroll
                for (int s = 0; s < 4; ++s) bx[s] = xfrag[(16 + s * 2 + h) * PIXB + pbase];
#pragma unroll
                for (int s = 0; s < 4; ++s) { MFMA1(ae0[s], bx[s]) }
            }
            {   // (2,0): bx0 re-read from LDS (keeps peak liveness low)
                uint4 bx[4];
#pragma unroll
                for (int s = 0; s < 4; ++s) bx[s] = xfrag[(s * 2 + h) * PIXB + pbase];
#pragma unroll
                for (int s = 0; s < 4; ++s) { MFMA1(a2[s], bx[s]) }
            }
            // fold: score = -acc; pack (score, code); running top-2
#pragma unroll
            for (int rg = 0; rg < 16; ++rg) {
                const unsigned long long mm =
                    pack_score(-acc[rg], cb + (rg & 3) + 8 * (rg >> 2) + 4 * h);
                if (pt == 0) { UPD2(p1a, p2a, mm) } else { UPD2(p1b, p2b, mm) }
            }
        }
    }
#undef MFMA1

    // combine the two lane-halves (disjoint code rows, same pixel col)
    {
        unsigned long long o1 = shfl_xor32_u64(p1a), o2 = shfl_xor32_u64(p2a);
        MRG2(p1a, p2a, o1, o2)
        o1 = shfl_xor32_u64(p1b); o2 = shfl_xor32_u64(p2b);
        MRG2(p1b, p2b, o1, o2)
        if (ln < 32) {
            red1[w][ln] = p1a; red2[w][ln] = p2a;
            red1[w][ln + 32] = p1b; red2[w][ln + 32] = p2b;
        }
    }
    __syncthreads();

    // ---- final top-2 across 8 waves + exact fp32 rescore (verified op order)
    if (tid < PIXB) {
        unsigned long long M1 = red1[0][tid], M2 = red2[0][tid];
#pragma unroll
        for (int wv = 1; wv < WAVES; ++wv) { MRG2(M1, M2, red1[wv][tid], red2[wv][tid]) }
        const int k1 = (int)(unsigned int)(M1 & 0xFFFFFFFFull);
        const int k2 = (int)(unsigned int)(M2 & 0xFFFFFFFFull);
        // exact fp32 rescore: dot = sequential fmaf over c; dist = fmaf(-2,dot,ee)
        float d1 = 0.f, d2 = 0.f;
        const float* xcol = x_raw + tid;
#pragma unroll 8
        for (int c = 0; c < C_DIM; ++c) {
            const float xv = xcol[c * PIXB];
            d1 = fmaf(xv, embed[c * K_EMB + k1], d1);
            d2 = fmaf(xv, embed[c * K_EMB + k2], d2);
        }
        const float dist1 = fmaf(-2.f, d1, g_ee[k1]);
        const float dist2 = fmaf(-2.f, d2, g_ee[k2]);
        const unsigned long long s1 = pack_score(dist1, k1);
        const unsigned long long s2 = pack_score(dist2, k2);
        const int   k     = (s1 < s2) ? k1 : k2;
        const float distw = (s1 < s2) ? dist1 : dist2;   // exact winner distance
        ksel[tid] = k;
        out_idx[n0 + tid] = (float)k;
        atomicAdd(g_counts + k, 1u);
        float dist = distw;    // ||x-q||^2 = ||x||^2 + dist
        for (int off = 32; off; off >>= 1) dist += __shfl_down(dist, off, 64);
        if (tid == 0) bdist = dist;
    }
    __syncthreads();

    // ---- quantize gather + coalesced store (1024 float4, 512 thr x 2)
#pragma unroll
    for (int i = 0; i < 2; ++i) {
        const int F = tid + i * 512;               // 0..1023
        const int c = F >> 4, p0 = (F & 15) << 2;
        float* oq = out_q + b * (C_DIM * HW) + c * HW + hw0 + p0;
        const float* er = embed + c * K_EMB;
        float4 q;
        q.x = er[ksel[p0 + 0]];
        q.y = er[ksel[p0 + 1]];
        q.z = er[ksel[p0 + 2]];
        q.w = er[ksel[p0 + 3]];
        *reinterpret_cast<float4*>(oq) = q;
    }
    if (tid == 0) {
        float ls = bdist;
#pragma unroll
        for (int wv = 0; wv < WAVES; ++wv) ls += lred[wv];
        atomicAdd(&g_lossAcc, ls);
    }
}

__global__ __launch_bounds__(1024) void k_scalar(float* __restrict__ out_loss,
                                                 float* __restrict__ out_perp) {
    __shared__ float red[16];
    const int tid = threadIdx.x;  // 0..1023
    float p = (float)g_counts[tid] * (1.0f / (float)N_PIX);
    float t = p * logf(p + 1e-10f);   // p==0 -> exactly 0, matches reference
    for (int off = 32; off; off >>= 1) t += __shfl_down(t, off, 64);
    if ((tid & 63) == 0) red[tid >> 6] = t;
    __syncthreads();
    if (tid == 0) {
        float s = 0.f;
#pragma unroll
        for (int i = 0; i < 16; ++i) s += red[i];
        *out_perp = expf(-s);
        *out_loss = 0.25f * g_lossAcc * (1.0f / (float)(N_PIX * C_DIM));
    }
}

extern "C" void kernel_launch(void* const* d_in, const int* in_sizes, int n_in,
                              void* d_out, int out_size, void* d_ws, size_t ws_size,
                              hipStream_t stream) {
    const float* inp   = (const float*)d_in[0];
    const float* embed = (const float*)d_in[1];
    float* out = (float*)d_out;

    k_prep<<<dim3(16), dim3(64), 0, stream>>>(embed);
    k_main<<<dim3(N_PIX / PIXB), dim3(512), 0, stream>>>(
        inp, embed, out + OUT_Q_OFF, out + OUT_IDX_OFF);
    k_scalar<<<dim3(1), dim3(1024), 0, stream>>>(out + OUT_LOSS_OFF,
                                                 out + OUT_PERP_OFF);
}

// Round 5
// 118.911 us; speedup vs baseline: 1.5799x; 1.5799x over previous
//
#include <hip/hip_runtime.h>

// Problem constants (inputs: (32,64,32,32) fp32; embed: (64,1024) fp32)
#define N_PIX  32768   // B*H*W
#define C_DIM  64
#define K_EMB  1024
#define HW     1024    // H*W
#define PIXB   32      // pixels per block (grid 1024 -> 4 blocks/CU TLP)

// d_out layout (float32, concatenated in return order):
//   quantized_out (B,C,H,W) | loss | encoding_indices | perplexity
#define OUT_Q_OFF    0
#define OUT_LOSS_OFF 2097152
#define OUT_IDX_OFF  2097153
#define OUT_PERP_OFF 2129921

typedef __attribute__((ext_vector_type(8)))  __bf16 bf16x8;
typedef __attribute__((ext_vector_type(16))) float  f32x16;

// g_esplit: bf16x3 split of embed, A-fragment-packed:
//   [j][tile(32 codes)][s(k/16)][h(k8 half)][c32][e(8)] -> 3*65536 shorts = 384 KB
__device__ unsigned short g_esplit[3 * K_EMB * C_DIM];
__device__ uint4          g_eesplit[2 * K_EMB];  // ee-slice A frags; [h][code], h=1 zero
__device__ float          g_ee[K_EMB];     // ||e_k||^2, fp32 fmaf chain (c-order)
__device__ unsigned int   g_counts[K_EMB];
__device__ float          g_lossAcc;

__device__ __forceinline__ unsigned short f2bf(float f) {   // RNE f32->bf16
    unsigned u = __float_as_uint(f);
    unsigned r = u + 0x7FFFu + ((u >> 16) & 1u);
    return (unsigned short)(r >> 16);
}
__device__ __forceinline__ float bf2f(unsigned short b) {
    return __uint_as_float(((unsigned)b) << 16);
}
__device__ __forceinline__ unsigned long long pack_score(float d, int k) {
    unsigned int u = __float_as_uint(d);
    u = (u & 0x80000000u) ? ~u : (u | 0x80000000u);  // monotone map, negative-safe
    return ((unsigned long long)u << 32) | (unsigned int)k;
}
__device__ __forceinline__ uint4 pack8(const unsigned short* v) {
    uint4 u;
    u.x = (unsigned)v[0] | ((unsigned)v[1] << 16);
    u.y = (unsigned)v[2] | ((unsigned)v[3] << 16);
    u.z = (unsigned)v[4] | ((unsigned)v[5] << 16);
    u.w = (unsigned)v[6] | ((unsigned)v[7] << 16);
    return u;
}
__device__ __forceinline__ unsigned long long shfl_xor32_u64(unsigned long long v) {
    unsigned lo = (unsigned)v, hi = (unsigned)(v >> 32);
    lo = __shfl_xor(lo, 32, 64);
    hi = __shfl_xor(hi, 32, 64);
    return ((unsigned long long)hi << 32) | lo;
}
// keep (P1 <= P2) as the two smallest seen so far
#define UPD2(P1, P2, MM) { \
    if ((MM) < P1) { P2 = P1; P1 = (MM); } else if ((MM) < P2) P2 = (MM); }
// merge sorted pair (o1<=o2) into (P1<=P2)
#define MRG2(P1, P2, O1, O2) { \
    unsigned long long _lo = (O1) < P1 ? (O1) : P1; \
    unsigned long long _hi = (O1) < P1 ? P1 : (O1); \
    unsigned long long _m2 = (O2) < P2 ? (O2) : P2; \
    P1 = _lo; P2 = _hi < _m2 ? _hi : _m2; }

// Split embed into bf16x3 A-fragment layout (uint4 stores) + ||e||^2 chain
// + ee-slice MFMA fragment (-0.5*||e||^2 split bf16x3 at K-elems 0..2).
__global__ void k_prep(const float* __restrict__ embed) {
    const int code = blockIdx.x * 64 + threadIdx.x;   // grid 16 x 64 -> 0..1023
    if (code == 0) g_lossAcc = 0.f;
    g_counts[code] = 0u;
    const int tile = code >> 5, c32 = code & 31;
    uint4* o = reinterpret_cast<uint4*>(g_esplit);
    float ee = 0.f;
#pragma unroll
    for (int s = 0; s < 4; ++s)
#pragma unroll
        for (int hh = 0; hh < 2; ++hh) {
            unsigned short b1[8], b2[8], b3[8];
#pragma unroll
            for (int e = 0; e < 8; ++e) {
                const float x = embed[(s * 16 + hh * 8 + e) * K_EMB + code];
                ee = fmaf(x, x, ee);                  // sequential c-order chain
                b1[e] = f2bf(x);
                const float r1 = x - bf2f(b1[e]);
                b2[e] = f2bf(r1);
                const float r2 = r1 - bf2f(b2[e]);
                b3[e] = f2bf(r2);
            }
            const int oi = tile * 256 + s * 64 + hh * 32 + c32;
            o[oi        ] = pack8(b1);
            o[oi +  8192] = pack8(b2);
            o[oi + 16384] = pack8(b3);
        }
    g_ee[code] = ee;
    // ee-slice A fragment: -0.5*ee split bf16x3 at K elements 0,1,2 (h=0 half)
    const float v = -0.5f * ee;
    const unsigned short e1 = f2bf(v);
    const float r1 = v - bf2f(e1);
    const unsigned short e2 = f2bf(r1);
    const float r2 = r1 - bf2f(e2);
    const unsigned short e3 = f2bf(r2);
    g_eesplit[code] = make_uint4((unsigned)e1 | ((unsigned)e2 << 16),
                                 (unsigned)e3, 0u, 0u);
    g_eesplit[K_EMB + code] = make_uint4(0u, 0u, 0u, 0u);
}

// Main: 32 pixels x 1024 codes per block, 256 threads (4 waves).
// R2's verified register regime ((256,2), ~120 VGPR, no spill); TLP doubled
// via grid=1024 -> 4 blocks/CU. NO launch-bounds-forced VGPR caps (R3/R4 lesson:
// any cap < ~120 VGPR causes catastrophic scratch spill in the A-frag loop).
__global__ __launch_bounds__(256, 2) void k_main(
    const float* __restrict__ inp, const float* __restrict__ embed,
    float* __restrict__ out_q, float* __restrict__ out_idx) {

    __shared__ float x_raw[C_DIM * PIXB];          // 8 KB raw fp32 tile [c][p]
    __shared__ uint4 xfrag[3 * 4 * 2 * PIXB];      // 12 KB [j][s][h][p] -> 16B frags
    __shared__ unsigned long long red1[4][PIXB];   // per-wave top-1
    __shared__ unsigned long long red2[4][PIXB];   // per-wave top-2
    __shared__ int   ksel[PIXB];
    __shared__ float lred[4];
    __shared__ float bdist;

    const int tid = threadIdx.x;
    const int n0  = blockIdx.x * PIXB;
    const int b   = n0 >> 10;
    const int hw0 = n0 & 1023;
    const float* __restrict__ xg = inp + b * (C_DIM * HW) + hw0;

    // ---- stage 1: coalesced raw tile load -> LDS (512 float4, 256 thr x 2)
#pragma unroll
    for (int i = 0; i < 2; ++i) {
        const int F = tid + i * 256;               // float4 index 0..511
        const int c = F >> 3, p4 = (F & 7) << 2;
        *reinterpret_cast<float4*>(&x_raw[F << 2]) =
            *reinterpret_cast<const float4*>(xg + c * HW + p4);
    }
    __syncthreads();

    // ---- stage 2: bf16x3 split into B-fragment layout + ||x||^2 partial
    float sx2 = 0.f;
    {
        const int s = tid >> 6, hh = (tid >> 5) & 1, p = tid & 31;  // 256 slots
        unsigned short b1[8], b2[8], b3[8];
#pragma unroll
        for (int e = 0; e < 8; ++e) {
            const float x = x_raw[(s * 16 + hh * 8 + e) * PIXB + p];
            sx2 = fmaf(x, x, sx2);
            b1[e] = f2bf(x);
            const float r1 = x - bf2f(b1[e]);
            b2[e] = f2bf(r1);
            const float r2 = r1 - bf2f(b2[e]);
            b3[e] = f2bf(r2);
        }
        const int fi = (s * 2 + hh) * PIXB + p;    // within one j-plane (8*PIXB)
        xfrag[fi            ] = pack8(b1);
        xfrag[fi + 8 * PIXB ] = pack8(b2);
        xfrag[fi + 16 * PIXB] = pack8(b3);
    }
    for (int off = 32; off; off >>= 1) sx2 += __shfl_down(sx2, off, 64);
    if ((tid & 63) == 0) lred[tid >> 6] = sx2;
    __syncthreads();

    // ---- distance GEMM + running top-2 (score = -(dot - ee/2))
    const int w   = tid >> 6;                      // wave 0..3
    const int ln  = tid & 63;
    const int c31 = ln & 31;
    const int h   = ln >> 5;
    const uint4* __restrict__ eg = reinterpret_cast<const uint4*>(g_esplit);
    const int abase = h * 32 + c31;
    const int pbase = c31;                         // single 32-pixel column

    unsigned long long p1a = ~0ull, p2a = ~0ull;   // pixel top-2
    const uint4 bones = make_uint4(h ? 0u : 0x3F803F80u, h ? 0u : 0x00003F80u, 0u, 0u);

#define MFMA1(AF, BF) \
    acc = __builtin_amdgcn_mfma_f32_32x32x16_bf16( \
        __builtin_bit_cast(bf16x8, AF), __builtin_bit_cast(bf16x8, BF), acc, 0, 0, 0);

#pragma unroll 1
    for (int r = 0; r < 8; ++r) {
        const int ct = r * 4 + w;                  // this wave's code tile 0..31
        const int b0 = ct * 256 + abase;
        const int cb = ct * 32;
        // A fragments for this tile: j0, j1, j2, ee (17 x uint4, issued up front)
        uint4 ae0[4], ae1[4], a2[4], aee;
#pragma unroll
        for (int s = 0; s < 4; ++s) {
            ae0[s] = eg[b0 + s * 64];
            ae1[s] = eg[b0 + 8192 + s * 64];
            a2[s]  = eg[b0 + 16384 + s * 64];
        }
        aee = g_eesplit[h * K_EMB + ct * 32 + c31];

        f32x16 acc = {};
        MFMA1(aee, bones)
        {   // (0,0),(1,0) then drop bx0 (re-read later for (2,0))
            uint4 bx[4];
#pragma unroll
            for (int s = 0; s < 4; ++s) bx[s] = xfrag[(s * 2 + h) * PIXB + pbase];
#pragma unroll
            for (int s = 0; s < 4; ++s) { MFMA1(ae0[s], bx[s]) }
#pragma unroll
            for (int s = 0; s < 4; ++s) { MFMA1(ae1[s], bx[s]) }
        }
        {   // (0,1),(1,1)
            uint4 bx[4];
#pragma unroll
            for (int s = 0; s < 4; ++s) bx[s] = xfrag[(8 + s * 2 + h) * PIXB + pbase];
#pragma unroll
            for (int s = 0; s < 4; ++s) { MFMA1(ae0[s], bx[s]) }
#pragma unroll
            for (int s = 0; s < 4; ++s) { MFMA1(ae1[s], bx[s]) }
        }
        {   // (0,2)
            uint4 bx[4];
#pragma unroll
            for (int s = 0; s < 4; ++s) bx[s] = xfrag[(16 + s * 2 + h) * PIXB + pbase];
#pragma unroll
            for (int s = 0; s < 4; ++s) { MFMA1(ae0[s], bx[s]) }
        }
        {   // (2,0): bx0 re-read from LDS (keeps peak liveness low)
            uint4 bx[4];
#pragma unroll
            for (int s = 0; s < 4; ++s) bx[s] = xfrag[(s * 2 + h) * PIXB + pbase];
#pragma unroll
            for (int s = 0; s < 4; ++s) { MFMA1(a2[s], bx[s]) }
        }
        // fold: score = -acc; pack (score, code); running top-2
#pragma unroll
        for (int rg = 0; rg < 16; ++rg) {
            const unsigned long long mm =
                pack_score(-acc[rg], cb + (rg & 3) + 8 * (rg >> 2) + 4 * h);
            UPD2(p1a, p2a, mm)
        }
    }
#undef MFMA1

    // combine the two lane-halves (disjoint code rows, same pixel col)
    {
        unsigned long long o1 = shfl_xor32_u64(p1a), o2 = shfl_xor32_u64(p2a);
        MRG2(p1a, p2a, o1, o2)
        if (ln < 32) { red1[w][ln] = p1a; red2[w][ln] = p2a; }
    }
    __syncthreads();

    // ---- final top-2 across 4 waves + exact fp32 rescore (verified op order)
    if (tid < PIXB) {
        unsigned long long M1 = red1[0][tid], M2 = red2[0][tid];
#pragma unroll
        for (int wv = 1; wv < 4; ++wv) { MRG2(M1, M2, red1[wv][tid], red2[wv][tid]) }
        const int k1 = (int)(unsigned int)(M1 & 0xFFFFFFFFull);
        const int k2 = (int)(unsigned int)(M2 & 0xFFFFFFFFull);
        // exact fp32 rescore: dot = sequential fmaf over c; dist = fmaf(-2,dot,ee)
        float d1 = 0.f, d2 = 0.f;
        const float* xcol = x_raw + tid;
#pragma unroll 8
        for (int c = 0; c < C_DIM; ++c) {
            const float xv = xcol[c * PIXB];
            d1 = fmaf(xv, embed[c * K_EMB + k1], d1);
            d2 = fmaf(xv, embed[c * K_EMB + k2], d2);
        }
        const float dist1 = fmaf(-2.f, d1, g_ee[k1]);
        const float dist2 = fmaf(-2.f, d2, g_ee[k2]);
        const unsigned long long s1 = pack_score(dist1, k1);
        const unsigned long long s2 = pack_score(dist2, k2);
        const int   k     = (s1 < s2) ? k1 : k2;
        const float distw = (s1 < s2) ? dist1 : dist2;   // exact winner distance
        ksel[tid] = k;
        out_idx[n0 + tid] = (float)k;
        atomicAdd(g_counts + k, 1u);
        // 32-lane sum (width 32: lanes 32..63 are inactive here!)
        float dist = distw;    // ||x-q||^2 = ||x||^2 + dist
        for (int off = 16; off; off >>= 1) dist += __shfl_down(dist, off, 32);
        if (tid == 0) bdist = dist;
    }
    __syncthreads();

    // ---- quantize gather + coalesced store (512 float4, 256 thr x 2)
#pragma unroll
    for (int i = 0; i < 2; ++i) {
        const int F = tid + i * 256;               // 0..511
        const int c = F >> 3, p0 = (F & 7) << 2;
        float* oq = out_q + b * (C_DIM * HW) + c * HW + hw0 + p0;
        const float* er = embed + c * K_EMB;
        float4 q;
        q.x = er[ksel[p0 + 0]];
        q.y = er[ksel[p0 + 1]];
        q.z = er[ksel[p0 + 2]];
        q.w = er[ksel[p0 + 3]];
        *reinterpret_cast<float4*>(oq) = q;
    }
    if (tid == 0)
        atomicAdd(&g_lossAcc, lred[0] + lred[1] + lred[2] + lred[3] + bdist);
}

__global__ __launch_bounds__(1024) void k_scalar(float* __restrict__ out_loss,
                                                 float* __restrict__ out_perp) {
    __shared__ float red[16];
    const int tid = threadIdx.x;  // 0..1023
    float p = (float)g_counts[tid] * (1.0f / (float)N_PIX);
    float t = p * logf(p + 1e-10f);   // p==0 -> exactly 0, matches reference
    for (int off = 32; off; off >>= 1) t += __shfl_down(t, off, 64);
    if ((tid & 63) == 0) red[tid >> 6] = t;
    __syncthreads();
    if (tid == 0) {
        float s = 0.f;
#pragma unroll
        for (int i = 0; i < 16; ++i) s += red[i];
        *out_perp = expf(-s);
        *out_loss = 0.25f * g_lossAcc * (1.0f / (float)(N_PIX * C_DIM));
    }
}

extern "C" void kernel_launch(void* const* d_in, const int* in_sizes, int n_in,
                              void* d_out, int out_size, void* d_ws, size_t ws_size,
                              hipStream_t stream) {
    const float* inp   = (const float*)d_in[0];
    const float* embed = (const float*)d_in[1];
    float* out = (float*)d_out;

    k_prep<<<dim3(16), dim3(64), 0, stream>>>(embed);
    k_main<<<dim3(N_PIX / PIXB), dim3(256), 0, stream>>>(
        inp, embed, out + OUT_Q_OFF, out + OUT_IDX_OFF);
    k_scalar<<<dim3(1), dim3(1024), 0, stream>>>(out + OUT_LOSS_OFF,
                                                 out + OUT_PERP_OFF);
}